// Round 10
// baseline (541.927 us; speedup 1.0000x reference)
//
#include <hip/hip_runtime.h>
#include <hip/hip_bf16.h>
#include <hip/hip_fp16.h>

// Problem constants (match reference)
#define NN 50000
#define EE 800000
#define INF_ 256
#define HH 4
#define DD 64
#define KK 3
#define NEG_SLOPE 0.2f

struct __align__(8) half4 { __half2 a, b; };
struct __align__(8) short4s { short a, b, c, d; };

using bf16x8 = __attribute__((ext_vector_type(8))) short;
using f32x4  = __attribute__((ext_vector_type(4))) float;

__device__ __forceinline__ float lrelu(float x) {
    return x >= 0.0f ? x : NEG_SLOPE * x;
}

__device__ __forceinline__ float wave_sum(float v) {
    #pragma unroll
    for (int m = 1; m < 64; m <<= 1) v += __shfl_xor(v, m, 64);
    return v;
}

// fp32 <-> bf16 (RN-even) bit helpers
__device__ __forceinline__ short f2bf(float f) {
    union { float f; unsigned u; } v; v.f = f;
    unsigned r = (v.u + 0x7FFFu + ((v.u >> 16) & 1u)) >> 16;
    return (short)r;
}
__device__ __forceinline__ float bf2f(short s) {
    union { unsigned u; float f; } v; v.u = ((unsigned)(unsigned short)s) << 16;
    return v.f;
}

// ---------------- W -> bf16 hi/lo (one-time, tiny)
__global__ __launch_bounds__(256) void conv_w(const float* __restrict__ W,
                                              short* __restrict__ Wh,
                                              short* __restrict__ Wl) {
    int i = blockIdx.x * 256 + threadIdx.x; // 65536 total
    float w = W[i];
    short h = f2bf(w);
    Wh[i] = h;
    Wl[i] = f2bf(w - bf2f(h));
}

// ---------------- MFMA GEMM: C[m,j] = sum_k feat[m,k] * W[j,k], fp32 via bf16 hi/lo split.
// Block: 32 rows x 256 cols. 4 waves; wave w = col-slab/head w. LDS = 32 KB (5 blocks/CU).
// A-panel staged in LDS as bf16 hi/lo with XOR swizzle (c ^= (row&7)<<3) on write AND read.
// Fused epilogue: el/er for head w from in-register acc; fp32 C + fp16 C16 outputs.
__global__ __launch_bounds__(256) void gemm_mfma(const float* __restrict__ A,
                                                 const short* __restrict__ Wh,
                                                 const short* __restrict__ Wl,
                                                 const float* __restrict__ al,
                                                 const float* __restrict__ ar,
                                                 float* __restrict__ C,
                                                 __half* __restrict__ C16,
                                                 float* __restrict__ el,
                                                 float* __restrict__ er, int M) {
    __shared__ short Ah[32 * 256];
    __shared__ short Al[32 * 256];
    int tid = threadIdx.x;
    int m0 = blockIdx.x * 32;

    // ---- stage A panel (32 x 256 fp32) -> bf16 hi/lo in LDS, swizzled
    {
        int r4 = tid >> 6;         // 0..3 row-within-iter
        int c4 = (tid & 63) * 4;   // col (multiple of 4)
        #pragma unroll
        for (int it = 0; it < 8; ++it) {
            int row = it * 4 + r4;
            int m = m0 + row;
            float4 v = (m < M) ? *(const float4*)&A[(size_t)m * 256 + c4]
                               : make_float4(0.f, 0.f, 0.f, 0.f);
            short h0 = f2bf(v.x), h1 = f2bf(v.y), h2 = f2bf(v.z), h3 = f2bf(v.w);
            short l0 = f2bf(v.x - bf2f(h0)), l1 = f2bf(v.y - bf2f(h1));
            short l2 = f2bf(v.z - bf2f(h2)), l3 = f2bf(v.w - bf2f(h3));
            int cs = c4 ^ ((row & 7) << 3);  // swizzled element offset (4-aligned preserved)
            short4s sh = { h0, h1, h2, h3 };
            short4s sl = { l0, l1, l2, l3 };
            *(short4s*)&Ah[row * 256 + cs] = sh;
            *(short4s*)&Al[row * 256 + cs] = sl;
        }
    }
    __syncthreads();

    int w = tid >> 6;        // wave = col-slab = head
    int lane = tid & 63;
    int lrow = lane & 15;    // row-in-tile (A) / col-in-tile (B,C)
    int lk = lane >> 4;      // k sub-chunk selector
    int j0 = w * 64;

    f32x4 acc[2][4] = {};    // [tm][tj]

    #pragma unroll
    for (int kc = 0; kc < 8; ++kc) {
        int kbase = kc * 32 + lk * 8;   // multiple of 8
        bf16x8 bh[4], bl[4], ah[2], alo[2];
        #pragma unroll
        for (int tj = 0; tj < 4; ++tj) {
            int j = j0 + tj * 16 + lrow;
            bh[tj] = *(const bf16x8*)&Wh[j * 256 + kbase];
            bl[tj] = *(const bf16x8*)&Wl[j * 256 + kbase];
        }
        #pragma unroll
        for (int tm = 0; tm < 2; ++tm) {
            int row = tm * 16 + lrow;
            int ks = kbase ^ ((row & 7) << 3);  // swizzled (8-aligned preserved)
            ah[tm]  = *(const bf16x8*)&Ah[row * 256 + ks];
            alo[tm] = *(const bf16x8*)&Al[row * 256 + ks];
        }
        #pragma unroll
        for (int tm = 0; tm < 2; ++tm)
            #pragma unroll
            for (int tj = 0; tj < 4; ++tj) {
                acc[tm][tj] = __builtin_amdgcn_mfma_f32_16x16x32_bf16(ah[tm],  bh[tj], acc[tm][tj], 0, 0, 0);
                acc[tm][tj] = __builtin_amdgcn_mfma_f32_16x16x32_bf16(alo[tm], bh[tj], acc[tm][tj], 0, 0, 0);
                acc[tm][tj] = __builtin_amdgcn_mfma_f32_16x16x32_bf16(ah[tm],  bl[tj], acc[tm][tj], 0, 0, 0);
            }
    }

    // ---- store C (fp32) + C16 (fp16). C/D layout: col = lane&15, row = (lane>>4)*4 + reg.
    #pragma unroll
    for (int tm = 0; tm < 2; ++tm)
        #pragma unroll
        for (int tj = 0; tj < 4; ++tj)
            #pragma unroll
            for (int r = 0; r < 4; ++r) {
                int m = m0 + tm * 16 + lk * 4 + r;
                if (m < M) {
                    int j = j0 + tj * 16 + lrow;
                    float x = acc[tm][tj][r];
                    C[(size_t)m * 256 + j] = x;
                    C16[(size_t)m * 256 + j] = __float2half(x);
                }
            }

    // ---- fused el/er epilogue for head w
    float alj[4], arj[4];
    #pragma unroll
    for (int tj = 0; tj < 4; ++tj) {
        alj[tj] = al[j0 + tj * 16 + lrow];
        arj[tj] = ar[j0 + tj * 16 + lrow];
    }
    #pragma unroll
    for (int tm = 0; tm < 2; ++tm)
        #pragma unroll
        for (int r = 0; r < 4; ++r) {
            float pl = acc[tm][0][r] * alj[0] + acc[tm][1][r] * alj[1] +
                       acc[tm][2][r] * alj[2] + acc[tm][3][r] * alj[3];
            float pr = acc[tm][0][r] * arj[0] + acc[tm][1][r] * arj[1] +
                       acc[tm][2][r] * arj[2] + acc[tm][3][r] * arj[3];
            #pragma unroll
            for (int msk = 1; msk < 16; msk <<= 1) {
                pl += __shfl_xor(pl, msk, 64);
                pr += __shfl_xor(pr, msk, 64);
            }
            if (lrow == 0) {
                int m = m0 + tm * 16 + lk * 4 + r;
                if (m < M) { el[m * 4 + w] = pl; er[m * 4 + w] = pr; }
            }
        }
}

// ---------------- CSR build
__global__ void count_k(const int* __restrict__ dst, int* __restrict__ cnt, int E) {
    int e = blockIdx.x * 256 + threadIdx.x;
    if (e < E) atomicAdd(&cnt[dst[e]], 1);
}

__global__ __launch_bounds__(256) void scan1(const int* __restrict__ counts,
                                             int* __restrict__ offs,
                                             int* __restrict__ bsums, int n) {
    __shared__ int sh[256];
    int b = blockIdx.x, t = threadIdx.x;
    int base = b * 1024 + t * 4;
    int v[4];
    #pragma unroll
    for (int i = 0; i < 4; ++i) v[i] = (base + i < n) ? counts[base + i] : 0;
    int tsum = v[0] + v[1] + v[2] + v[3];
    sh[t] = tsum; __syncthreads();
    for (int off = 1; off < 256; off <<= 1) {
        int x = (t >= off) ? sh[t - off] : 0;
        __syncthreads();
        sh[t] += x;
        __syncthreads();
    }
    int run = sh[t] - tsum;
    #pragma unroll
    for (int i = 0; i < 4; ++i) { if (base + i < n) offs[base + i] = run; run += v[i]; }
    if (t == 255) bsums[b] = sh[255];
}

__global__ void scan2(int* bsums, int nb) {
    if (threadIdx.x == 0 && blockIdx.x == 0) {
        int run = 0;
        for (int i = 0; i < nb; ++i) { int v = bsums[i]; bsums[i] = run; run += v; }
    }
}

__global__ __launch_bounds__(256) void scan3(int* __restrict__ offs,
                                             const int* __restrict__ bsums,
                                             int* __restrict__ cursor, int n, int E) {
    int b = blockIdx.x;
    int base = b * 1024 + threadIdx.x * 4;
    int add = bsums[b];
    #pragma unroll
    for (int i = 0; i < 4; ++i) {
        if (base + i < n) {
            int v = offs[base + i] + add;
            offs[base + i] = v;
            cursor[base + i] = v;
        }
    }
    if (b == 0 && threadIdx.x == 0) offs[n] = E;
}

// ---------------- scatter edges into CSR slots + compute leaky logits
__global__ void scatter_edges(const int* __restrict__ src, const int* __restrict__ dst,
                              const float4* __restrict__ el4, const float4* __restrict__ er4,
                              int* __restrict__ cursor, int* __restrict__ ssrc,
                              float4* __restrict__ alog, int E) {
    int e = blockIdx.x * 256 + threadIdx.x;
    if (e >= E) return;
    int s = src[e], d = dst[e];
    int slot = atomicAdd(&cursor[d], 1);
    ssrc[slot] = s;
    float4 a = el4[s], b = er4[d];
    float4 o;
    o.x = lrelu(a.x + b.x);
    o.y = lrelu(a.y + b.y);
    o.z = lrelu(a.z + b.z);
    o.w = lrelu(a.w + b.w);
    alog[slot] = o;
}

// ---------------- per-(node,head) edge softmax (in place on alog)
__global__ __launch_bounds__(256) void edge_softmax(const int* __restrict__ offs,
                                                    float* __restrict__ alog, int n) {
    int t = blockIdx.x * 256 + threadIdx.x;
    if (t >= n * 4) return;
    int node = t >> 2, h = t & 3;
    int o0 = offs[node], o1 = offs[node + 1];
    if (o0 >= o1) return;
    float m = -1e30f;
    for (int i = o0; i < o1; ++i) m = fmaxf(m, alog[i * 4 + h]);
    float s = 0.f;
    for (int i = o0; i < o1; ++i) {
        float v = expf(alog[i * 4 + h] - m);
        alog[i * 4 + h] = v;
        s += v;
    }
    float inv = 1.0f / s;
    for (int i = o0; i < o1; ++i) alog[i * 4 + h] *= inv;
}

// ---------------- one diffusion hop (fp16 gather, fp32 accumulate, fp16 store)
// One WAVE per node: 64 lanes x 4 halves (8 B) = the full 256-col row (512 B/edge).
__global__ __launch_bounds__(256) void hop_kernel(const int* __restrict__ offs,
                                                  const int* __restrict__ ssrc,
                                                  const float* __restrict__ alog,
                                                  const __half* __restrict__ hin,
                                                  __half* __restrict__ hout) {
    int w = threadIdx.x >> 6;
    int n = blockIdx.x * 4 + w;
    if (n >= NN) return;
    int lane = threadIdx.x & 63;
    int h = lane >> 4;
    int col = lane * 4;
    int o0 = offs[n], o1 = offs[n + 1];
    float4 acc0 = make_float4(0.f, 0.f, 0.f, 0.f);
    float4 acc1 = make_float4(0.f, 0.f, 0.f, 0.f);
    float4 acc2 = make_float4(0.f, 0.f, 0.f, 0.f);
    float4 acc3 = make_float4(0.f, 0.f, 0.f, 0.f);
    int i = o0;
    for (; i + 4 <= o1; i += 4) {
        int s0 = ssrc[i], s1 = ssrc[i + 1], s2 = ssrc[i + 2], s3 = ssrc[i + 3];
        float a0 = alog[i * 4 + h];
        float a1 = alog[(i + 1) * 4 + h];
        float a2 = alog[(i + 2) * 4 + h];
        float a3 = alog[(i + 3) * 4 + h];
        half4 v0 = *(const half4*)&hin[(size_t)s0 * 256 + col];
        half4 v1 = *(const half4*)&hin[(size_t)s1 * 256 + col];
        half4 v2 = *(const half4*)&hin[(size_t)s2 * 256 + col];
        half4 v3 = *(const half4*)&hin[(size_t)s3 * 256 + col];
        float2 f0a = __half22float2(v0.a), f0b = __half22float2(v0.b);
        float2 f1a = __half22float2(v1.a), f1b = __half22float2(v1.b);
        float2 f2a = __half22float2(v2.a), f2b = __half22float2(v2.b);
        float2 f3a = __half22float2(v3.a), f3b = __half22float2(v3.b);
        acc0.x = fmaf(a0, f0a.x, acc0.x); acc0.y = fmaf(a0, f0a.y, acc0.y);
        acc0.z = fmaf(a0, f0b.x, acc0.z); acc0.w = fmaf(a0, f0b.y, acc0.w);
        acc1.x = fmaf(a1, f1a.x, acc1.x); acc1.y = fmaf(a1, f1a.y, acc1.y);
        acc1.z = fmaf(a1, f1b.x, acc1.z); acc1.w = fmaf(a1, f1b.y, acc1.w);
        acc2.x = fmaf(a2, f2a.x, acc2.x); acc2.y = fmaf(a2, f2a.y, acc2.y);
        acc2.z = fmaf(a2, f2b.x, acc2.z); acc2.w = fmaf(a2, f2b.y, acc2.w);
        acc3.x = fmaf(a3, f3a.x, acc3.x); acc3.y = fmaf(a3, f3a.y, acc3.y);
        acc3.z = fmaf(a3, f3b.x, acc3.z); acc3.w = fmaf(a3, f3b.y, acc3.w);
    }
    for (; i < o1; ++i) {
        int s0 = ssrc[i];
        float a0 = alog[i * 4 + h];
        half4 v0 = *(const half4*)&hin[(size_t)s0 * 256 + col];
        float2 f0a = __half22float2(v0.a), f0b = __half22float2(v0.b);
        acc0.x = fmaf(a0, f0a.x, acc0.x); acc0.y = fmaf(a0, f0a.y, acc0.y);
        acc0.z = fmaf(a0, f0b.x, acc0.z); acc0.w = fmaf(a0, f0b.y, acc0.w);
    }
    float4 r;
    r.x = (acc0.x + acc1.x) + (acc2.x + acc3.x);
    r.y = (acc0.y + acc1.y) + (acc2.y + acc3.y);
    r.z = (acc0.z + acc1.z) + (acc2.z + acc3.z);
    r.w = (acc0.w + acc1.w) + (acc2.w + acc3.w);
    half4 q;
    q.a = __floats2half2_rn(r.x, r.y);
    q.b = __floats2half2_rn(r.z, r.w);
    *(half4*)&hout[(size_t)n * 256 + col] = q;
}

// ---------------- hop attention epilogue (h0 fp32; h1..h3 fp16)
__global__ __launch_bounds__(256) void hop_attn(const float* __restrict__ h0,
                                                const __half* __restrict__ h1,
                                                const __half* __restrict__ h2,
                                                const __half* __restrict__ h3,
                                                const float* __restrict__ pos,
                                                const float* __restrict__ hl,
                                                const float* __restrict__ hr,
                                                const float* __restrict__ bias,
                                                float* __restrict__ out) {
    int n = blockIdx.x, tid = threadIdx.x;
    int h = tid >> 6, d = tid & 63;
    size_t idx = (size_t)n * 256 + tid;
    float v0 = h0[idx] + pos[(h * 4 + 0) * 64 + d];
    float v1 = __half2float(h1[idx]) + pos[(h * 4 + 1) * 64 + d];
    float v2 = __half2float(h2[idx]) + pos[(h * 4 + 2) * 64 + d];
    float v3 = __half2float(h3[idx]) + pos[(h * 4 + 3) * 64 + d];
    float wl = hl[tid], wr = hr[tid];
    float r0 = wave_sum(v0 * wl);
    float r1 = wave_sum(v1 * wl);
    float r2 = wave_sum(v2 * wl);
    float r3 = wave_sum(v3 * wl);
    float ar = wave_sum(v0 * wr);
    float l0 = lrelu(r0 + ar), l1 = lrelu(r1 + ar), l2 = lrelu(r2 + ar), l3 = lrelu(r3 + ar);
    float mm = fmaxf(fmaxf(l0, l1), fmaxf(l2, l3));
    float e0 = expf(l0 - mm), e1 = expf(l1 - mm), e2 = expf(l2 - mm), e3 = expf(l3 - mm);
    float inv = 1.0f / (e0 + e1 + e2 + e3);
    out[idx] = (v0 * e0 + v1 * e1 + v2 * e2 + v3 * e3) * inv + bias[tid];
}

extern "C" void kernel_launch(void* const* d_in, const int* in_sizes, int n_in,
                              void* d_out, int out_size, void* d_ws, size_t ws_size,
                              hipStream_t stream) {
    const float* feat   = (const float*)d_in[0];
    const int*   src    = (const int*)d_in[1];
    const int*   dst    = (const int*)d_in[2];
    const float* W_src  = (const float*)d_in[3];
    const float* attn_l = (const float*)d_in[4];
    const float* attn_r = (const float*)d_in[5];
    const float* hop_l  = (const float*)d_in[6];
    const float* hop_r  = (const float*)d_in[7];
    const float* pos    = (const float*)d_in[8];
    const float* bias   = (const float*)d_in[9];
    float* out = (float*)d_out;

    // workspace carve
    char* p = (char*)d_ws;
    auto alloc = [&](size_t bytes) {
        char* r = p;
        p += (bytes + 255) & ~(size_t)255;
        return r;
    };
    float*  fs   = (float*)alloc((size_t)NN * 256 * 4);   // h0 fp32 (epilogue exactness)
    __half* fs16 = (__half*)alloc((size_t)NN * 256 * 2);  // h0 fp16 (gather copy)
    __half* h1   = (__half*)alloc((size_t)NN * 256 * 2);
    __half* h2   = (__half*)alloc((size_t)NN * 256 * 2);
    __half* h3   = (__half*)alloc((size_t)NN * 256 * 2);
    int*   offs = (int*)alloc((size_t)(NN + 1) * 4);
    int*   cnt  = (int*)alloc((size_t)NN * 4);
    int*   cur  = (int*)alloc((size_t)NN * 4);
    int*   bsum = (int*)alloc(256);
    float* el   = (float*)alloc((size_t)NN * 4 * 4);
    float* er   = (float*)alloc((size_t)NN * 4 * 4);
    int*   ssrc = (int*)alloc((size_t)EE * 4);
    float* alog = (float*)alloc((size_t)EE * 4 * 4);
    short* Wh   = (short*)alloc((size_t)256 * 256 * 2);
    short* Wl   = (short*)alloc((size_t)256 * 256 * 2);

    const int nScan = (NN + 1023) / 1024; // 49

    // 1) W -> bf16 hi/lo, then feat_src = feat @ W^T via MFMA (fused el/er + fp16 copy)
    conv_w<<<256, 256, 0, stream>>>(W_src, Wh, Wl);
    gemm_mfma<<<(NN + 31) / 32, 256, 0, stream>>>(feat, Wh, Wl, attn_l, attn_r,
                                                  fs, fs16, el, er, NN);
    // 2) CSR build
    hipMemsetAsync(cnt, 0, (size_t)NN * 4, stream);
    count_k<<<(EE + 255) / 256, 256, 0, stream>>>(dst, cnt, EE);
    scan1<<<nScan, 256, 0, stream>>>(cnt, offs, bsum, NN);
    scan2<<<1, 64, 0, stream>>>(bsum, nScan);
    scan3<<<nScan, 256, 0, stream>>>(offs, bsum, cur, NN, EE);
    scatter_edges<<<(EE + 255) / 256, 256, 0, stream>>>(src, dst, (const float4*)el,
                                                        (const float4*)er, cur, ssrc,
                                                        (float4*)alog, EE);
    // 3) edge softmax
    edge_softmax<<<(NN * 4 + 255) / 256, 256, 0, stream>>>(offs, alog, NN);
    // 4) K=3 diffusion hops, fp16 state; one wave per node
    hop_kernel<<<(NN + 3) / 4, 256, 0, stream>>>(offs, ssrc, alog, fs16, h1);
    hop_kernel<<<(NN + 3) / 4, 256, 0, stream>>>(offs, ssrc, alog, h1, h2);
    hop_kernel<<<(NN + 3) / 4, 256, 0, stream>>>(offs, ssrc, alog, h2, h3);
    // 5) hop attention epilogue
    hop_attn<<<NN, 256, 0, stream>>>(fs, h1, h2, h3, pos, hop_l, hop_r, bias, out);
}

// Round 11
// 515.157 us; speedup vs baseline: 1.0520x; 1.0520x over previous
//
#include <hip/hip_runtime.h>
#include <hip/hip_bf16.h>
#include <hip/hip_fp16.h>

// Problem constants (match reference)
#define NN 50000
#define EE 800000
#define INF_ 256
#define HH 4
#define DD 64
#define KK 3
#define NEG_SLOPE 0.2f

struct __align__(8) half4 { __half2 a, b; };
struct __align__(8) short4s { short a, b, c, d; };

using bf16x8 = __attribute__((ext_vector_type(8))) short;
using f32x4  = __attribute__((ext_vector_type(4))) float;

__device__ __forceinline__ float lrelu(float x) {
    return x >= 0.0f ? x : NEG_SLOPE * x;
}

__device__ __forceinline__ float wave_sum(float v) {
    #pragma unroll
    for (int m = 1; m < 64; m <<= 1) v += __shfl_xor(v, m, 64);
    return v;
}

// fp32 <-> bf16 (RN-even) bit helpers
__device__ __forceinline__ short f2bf(float f) {
    union { float f; unsigned u; } v; v.f = f;
    unsigned r = (v.u + 0x7FFFu + ((v.u >> 16) & 1u)) >> 16;
    return (short)r;
}
__device__ __forceinline__ float bf2f(short s) {
    union { unsigned u; float f; } v; v.u = ((unsigned)(unsigned short)s) << 16;
    return v.f;
}

// ---------------- W -> bf16 hi/lo in MFMA-FRAGMENT ORDER (one-time, tiny).
// Fragment layout: element i = ((((w*8+kc)*4+tj)*64+lane)*8+e  maps to
// j = w*64 + tj*16 + (lane&15), k = kc*32 + (lane>>4)*8 + e.
// In the GEMM, wave w's B-load for (kc,tj) is then base + lane*16B  -> fully coalesced.
__global__ __launch_bounds__(256) void conv_w(const float* __restrict__ W,
                                              short* __restrict__ Wh,
                                              short* __restrict__ Wl) {
    int i = blockIdx.x * 256 + threadIdx.x; // 65536 total
    int e    = i & 7;
    int lane = (i >> 3) & 63;
    int tj   = (i >> 9) & 3;
    int kc   = (i >> 11) & 7;
    int w    = i >> 14;
    int j = w * 64 + tj * 16 + (lane & 15);
    int k = kc * 32 + (lane >> 4) * 8 + e;
    float v = W[j * 256 + k];
    short h = f2bf(v);
    Wh[i] = h;
    Wl[i] = f2bf(v - bf2f(h));
}

// ---------------- MFMA GEMM: C[m,j] = sum_k feat[m,k] * W[j,k], fp32 via bf16 hi/lo split.
// Block: 32 rows x 256 cols. 4 waves; wave w = col-slab/head w. LDS = 32 KB.
// A-panel staged in LDS as bf16 hi/lo with XOR swizzle (c ^= (row&7)<<3) on write AND read.
// B loaded coalesced from fragment-ordered Wh/Wl. Fused el/er epilogue.
__global__ __launch_bounds__(256) void gemm_mfma(const float* __restrict__ A,
                                                 const short* __restrict__ Wh,
                                                 const short* __restrict__ Wl,
                                                 const float* __restrict__ al,
                                                 const float* __restrict__ ar,
                                                 float* __restrict__ C,
                                                 __half* __restrict__ C16,
                                                 float* __restrict__ el,
                                                 float* __restrict__ er, int M) {
    __shared__ short Ah[32 * 256];
    __shared__ short Al[32 * 256];
    int tid = threadIdx.x;
    int m0 = blockIdx.x * 32;

    // ---- stage A panel (32 x 256 fp32) -> bf16 hi/lo in LDS, swizzled
    {
        int r4 = tid >> 6;         // 0..3 row-within-iter
        int c4 = (tid & 63) * 4;   // col (multiple of 4)
        #pragma unroll
        for (int it = 0; it < 8; ++it) {
            int row = it * 4 + r4;
            int m = m0 + row;
            float4 v = (m < M) ? *(const float4*)&A[(size_t)m * 256 + c4]
                               : make_float4(0.f, 0.f, 0.f, 0.f);
            short h0 = f2bf(v.x), h1 = f2bf(v.y), h2 = f2bf(v.z), h3 = f2bf(v.w);
            short l0 = f2bf(v.x - bf2f(h0)), l1 = f2bf(v.y - bf2f(h1));
            short l2 = f2bf(v.z - bf2f(h2)), l3 = f2bf(v.w - bf2f(h3));
            int cs = c4 ^ ((row & 7) << 3);  // swizzled element offset (4-aligned preserved)
            short4s sh = { h0, h1, h2, h3 };
            short4s sl = { l0, l1, l2, l3 };
            *(short4s*)&Ah[row * 256 + cs] = sh;
            *(short4s*)&Al[row * 256 + cs] = sl;
        }
    }
    __syncthreads();

    int w = tid >> 6;        // wave = col-slab = head
    int lane = tid & 63;
    int lrow = lane & 15;    // row-in-tile (A) / col-in-tile (B,C)
    int lk = lane >> 4;      // k sub-chunk selector
    int j0 = w * 64;

    f32x4 acc[2][4] = {};    // [tm][tj]

    #pragma unroll
    for (int kc = 0; kc < 8; ++kc) {
        int kbase = kc * 32 + lk * 8;   // multiple of 8
        // fragment-ordered coalesced B loads: chunk index = ((w*8+kc)*4+tj)*64 + lane
        int fbase = (((w * 8 + kc) * 4) * 64 + lane) * 8;
        bf16x8 bh[4], bl[4], ah[2], alo[2];
        #pragma unroll
        for (int tj = 0; tj < 4; ++tj) {
            bh[tj] = *(const bf16x8*)&Wh[fbase + tj * 64 * 8];
            bl[tj] = *(const bf16x8*)&Wl[fbase + tj * 64 * 8];
        }
        #pragma unroll
        for (int tm = 0; tm < 2; ++tm) {
            int row = tm * 16 + lrow;
            int ks = kbase ^ ((row & 7) << 3);  // swizzled (8-aligned preserved)
            ah[tm]  = *(const bf16x8*)&Ah[row * 256 + ks];
            alo[tm] = *(const bf16x8*)&Al[row * 256 + ks];
        }
        #pragma unroll
        for (int tm = 0; tm < 2; ++tm)
            #pragma unroll
            for (int tj = 0; tj < 4; ++tj) {
                acc[tm][tj] = __builtin_amdgcn_mfma_f32_16x16x32_bf16(ah[tm],  bh[tj], acc[tm][tj], 0, 0, 0);
                acc[tm][tj] = __builtin_amdgcn_mfma_f32_16x16x32_bf16(alo[tm], bh[tj], acc[tm][tj], 0, 0, 0);
                acc[tm][tj] = __builtin_amdgcn_mfma_f32_16x16x32_bf16(ah[tm],  bl[tj], acc[tm][tj], 0, 0, 0);
            }
    }

    // ---- store C (fp32) + C16 (fp16). C/D layout: col = lane&15, row = (lane>>4)*4 + reg.
    #pragma unroll
    for (int tm = 0; tm < 2; ++tm)
        #pragma unroll
        for (int tj = 0; tj < 4; ++tj)
            #pragma unroll
            for (int r = 0; r < 4; ++r) {
                int m = m0 + tm * 16 + lk * 4 + r;
                if (m < M) {
                    int j = j0 + tj * 16 + lrow;
                    float x = acc[tm][tj][r];
                    C[(size_t)m * 256 + j] = x;
                    C16[(size_t)m * 256 + j] = __float2half(x);
                }
            }

    // ---- fused el/er epilogue for head w
    float alj[4], arj[4];
    #pragma unroll
    for (int tj = 0; tj < 4; ++tj) {
        alj[tj] = al[j0 + tj * 16 + lrow];
        arj[tj] = ar[j0 + tj * 16 + lrow];
    }
    #pragma unroll
    for (int tm = 0; tm < 2; ++tm)
        #pragma unroll
        for (int r = 0; r < 4; ++r) {
            float pl = acc[tm][0][r] * alj[0] + acc[tm][1][r] * alj[1] +
                       acc[tm][2][r] * alj[2] + acc[tm][3][r] * alj[3];
            float pr = acc[tm][0][r] * arj[0] + acc[tm][1][r] * arj[1] +
                       acc[tm][2][r] * arj[2] + acc[tm][3][r] * arj[3];
            #pragma unroll
            for (int msk = 1; msk < 16; msk <<= 1) {
                pl += __shfl_xor(pl, msk, 64);
                pr += __shfl_xor(pr, msk, 64);
            }
            if (lrow == 0) {
                int m = m0 + tm * 16 + lk * 4 + r;
                if (m < M) { el[m * 4 + w] = pl; er[m * 4 + w] = pr; }
            }
        }
}

// ---------------- CSR build
__global__ void count_k(const int* __restrict__ dst, int* __restrict__ cnt, int E) {
    int e = blockIdx.x * 256 + threadIdx.x;
    if (e < E) atomicAdd(&cnt[dst[e]], 1);
}

__global__ __launch_bounds__(256) void scan1(const int* __restrict__ counts,
                                             int* __restrict__ offs,
                                             int* __restrict__ bsums, int n) {
    __shared__ int sh[256];
    int b = blockIdx.x, t = threadIdx.x;
    int base = b * 1024 + t * 4;
    int v[4];
    #pragma unroll
    for (int i = 0; i < 4; ++i) v[i] = (base + i < n) ? counts[base + i] : 0;
    int tsum = v[0] + v[1] + v[2] + v[3];
    sh[t] = tsum; __syncthreads();
    for (int off = 1; off < 256; off <<= 1) {
        int x = (t >= off) ? sh[t - off] : 0;
        __syncthreads();
        sh[t] += x;
        __syncthreads();
    }
    int run = sh[t] - tsum;
    #pragma unroll
    for (int i = 0; i < 4; ++i) { if (base + i < n) offs[base + i] = run; run += v[i]; }
    if (t == 255) bsums[b] = sh[255];
}

__global__ void scan2(int* bsums, int nb) {
    if (threadIdx.x == 0 && blockIdx.x == 0) {
        int run = 0;
        for (int i = 0; i < nb; ++i) { int v = bsums[i]; bsums[i] = run; run += v; }
    }
}

__global__ __launch_bounds__(256) void scan3(int* __restrict__ offs,
                                             const int* __restrict__ bsums,
                                             int* __restrict__ cursor, int n, int E) {
    int b = blockIdx.x;
    int base = b * 1024 + threadIdx.x * 4;
    int add = bsums[b];
    #pragma unroll
    for (int i = 0; i < 4; ++i) {
        if (base + i < n) {
            int v = offs[base + i] + add;
            offs[base + i] = v;
            cursor[base + i] = v;
        }
    }
    if (b == 0 && threadIdx.x == 0) offs[n] = E;
}

// ---------------- scatter edges into CSR slots + compute leaky logits
__global__ void scatter_edges(const int* __restrict__ src, const int* __restrict__ dst,
                              const float4* __restrict__ el4, const float4* __restrict__ er4,
                              int* __restrict__ cursor, int* __restrict__ ssrc,
                              float4* __restrict__ alog, int E) {
    int e = blockIdx.x * 256 + threadIdx.x;
    if (e >= E) return;
    int s = src[e], d = dst[e];
    int slot = atomicAdd(&cursor[d], 1);
    ssrc[slot] = s;
    float4 a = el4[s], b = er4[d];
    float4 o;
    o.x = lrelu(a.x + b.x);
    o.y = lrelu(a.y + b.y);
    o.z = lrelu(a.z + b.z);
    o.w = lrelu(a.w + b.w);
    alog[slot] = o;
}

// ---------------- per-(node,head) edge softmax (in place on alog)
__global__ __launch_bounds__(256) void edge_softmax(const int* __restrict__ offs,
                                                    float* __restrict__ alog, int n) {
    int t = blockIdx.x * 256 + threadIdx.x;
    if (t >= n * 4) return;
    int node = t >> 2, h = t & 3;
    int o0 = offs[node], o1 = offs[node + 1];
    if (o0 >= o1) return;
    float m = -1e30f;
    for (int i = o0; i < o1; ++i) m = fmaxf(m, alog[i * 4 + h]);
    float s = 0.f;
    for (int i = o0; i < o1; ++i) {
        float v = expf(alog[i * 4 + h] - m);
        alog[i * 4 + h] = v;
        s += v;
    }
    float inv = 1.0f / s;
    for (int i = o0; i < o1; ++i) alog[i * 4 + h] *= inv;
}

// ---------------- one diffusion hop (fp16 gather, fp32 accumulate, fp16 store)
// One WAVE per node: 64 lanes x 4 halves (8 B) = the full 256-col row (512 B/edge).
__global__ __launch_bounds__(256) void hop_kernel(const int* __restrict__ offs,
                                                  const int* __restrict__ ssrc,
                                                  const float* __restrict__ alog,
                                                  const __half* __restrict__ hin,
                                                  __half* __restrict__ hout) {
    int w = threadIdx.x >> 6;
    int n = blockIdx.x * 4 + w;
    if (n >= NN) return;
    int lane = threadIdx.x & 63;
    int h = lane >> 4;
    int col = lane * 4;
    int o0 = offs[n], o1 = offs[n + 1];
    float4 acc0 = make_float4(0.f, 0.f, 0.f, 0.f);
    float4 acc1 = make_float4(0.f, 0.f, 0.f, 0.f);
    float4 acc2 = make_float4(0.f, 0.f, 0.f, 0.f);
    float4 acc3 = make_float4(0.f, 0.f, 0.f, 0.f);
    int i = o0;
    for (; i + 4 <= o1; i += 4) {
        int s0 = ssrc[i], s1 = ssrc[i + 1], s2 = ssrc[i + 2], s3 = ssrc[i + 3];
        float a0 = alog[i * 4 + h];
        float a1 = alog[(i + 1) * 4 + h];
        float a2 = alog[(i + 2) * 4 + h];
        float a3 = alog[(i + 3) * 4 + h];
        half4 v0 = *(const half4*)&hin[(size_t)s0 * 256 + col];
        half4 v1 = *(const half4*)&hin[(size_t)s1 * 256 + col];
        half4 v2 = *(const half4*)&hin[(size_t)s2 * 256 + col];
        half4 v3 = *(const half4*)&hin[(size_t)s3 * 256 + col];
        float2 f0a = __half22float2(v0.a), f0b = __half22float2(v0.b);
        float2 f1a = __half22float2(v1.a), f1b = __half22float2(v1.b);
        float2 f2a = __half22float2(v2.a), f2b = __half22float2(v2.b);
        float2 f3a = __half22float2(v3.a), f3b = __half22float2(v3.b);
        acc0.x = fmaf(a0, f0a.x, acc0.x); acc0.y = fmaf(a0, f0a.y, acc0.y);
        acc0.z = fmaf(a0, f0b.x, acc0.z); acc0.w = fmaf(a0, f0b.y, acc0.w);
        acc1.x = fmaf(a1, f1a.x, acc1.x); acc1.y = fmaf(a1, f1a.y, acc1.y);
        acc1.z = fmaf(a1, f1b.x, acc1.z); acc1.w = fmaf(a1, f1b.y, acc1.w);
        acc2.x = fmaf(a2, f2a.x, acc2.x); acc2.y = fmaf(a2, f2a.y, acc2.y);
        acc2.z = fmaf(a2, f2b.x, acc2.z); acc2.w = fmaf(a2, f2b.y, acc2.w);
        acc3.x = fmaf(a3, f3a.x, acc3.x); acc3.y = fmaf(a3, f3a.y, acc3.y);
        acc3.z = fmaf(a3, f3b.x, acc3.z); acc3.w = fmaf(a3, f3b.y, acc3.w);
    }
    for (; i < o1; ++i) {
        int s0 = ssrc[i];
        float a0 = alog[i * 4 + h];
        half4 v0 = *(const half4*)&hin[(size_t)s0 * 256 + col];
        float2 f0a = __half22float2(v0.a), f0b = __half22float2(v0.b);
        acc0.x = fmaf(a0, f0a.x, acc0.x); acc0.y = fmaf(a0, f0a.y, acc0.y);
        acc0.z = fmaf(a0, f0b.x, acc0.z); acc0.w = fmaf(a0, f0b.y, acc0.w);
    }
    float4 r;
    r.x = (acc0.x + acc1.x) + (acc2.x + acc3.x);
    r.y = (acc0.y + acc1.y) + (acc2.y + acc3.y);
    r.z = (acc0.z + acc1.z) + (acc2.z + acc3.z);
    r.w = (acc0.w + acc1.w) + (acc2.w + acc3.w);
    half4 q;
    q.a = __floats2half2_rn(r.x, r.y);
    q.b = __floats2half2_rn(r.z, r.w);
    *(half4*)&hout[(size_t)n * 256 + col] = q;
}

// ---------------- hop attention epilogue (h0 fp32; h1..h3 fp16)
__global__ __launch_bounds__(256) void hop_attn(const float* __restrict__ h0,
                                                const __half* __restrict__ h1,
                                                const __half* __restrict__ h2,
                                                const __half* __restrict__ h3,
                                                const float* __restrict__ pos,
                                                const float* __restrict__ hl,
                                                const float* __restrict__ hr,
                                                const float* __restrict__ bias,
                                                float* __restrict__ out) {
    int n = blockIdx.x, tid = threadIdx.x;
    int h = tid >> 6, d = tid & 63;
    size_t idx = (size_t)n * 256 + tid;
    float v0 = h0[idx] + pos[(h * 4 + 0) * 64 + d];
    float v1 = __half2float(h1[idx]) + pos[(h * 4 + 1) * 64 + d];
    float v2 = __half2float(h2[idx]) + pos[(h * 4 + 2) * 64 + d];
    float v3 = __half2float(h3[idx]) + pos[(h * 4 + 3) * 64 + d];
    float wl = hl[tid], wr = hr[tid];
    float r0 = wave_sum(v0 * wl);
    float r1 = wave_sum(v1 * wl);
    float r2 = wave_sum(v2 * wl);
    float r3 = wave_sum(v3 * wl);
    float ar = wave_sum(v0 * wr);
    float l0 = lrelu(r0 + ar), l1 = lrelu(r1 + ar), l2 = lrelu(r2 + ar), l3 = lrelu(r3 + ar);
    float mm = fmaxf(fmaxf(l0, l1), fmaxf(l2, l3));
    float e0 = expf(l0 - mm), e1 = expf(l1 - mm), e2 = expf(l2 - mm), e3 = expf(l3 - mm);
    float inv = 1.0f / (e0 + e1 + e2 + e3);
    out[idx] = (v0 * e0 + v1 * e1 + v2 * e2 + v3 * e3) * inv + bias[tid];
}

extern "C" void kernel_launch(void* const* d_in, const int* in_sizes, int n_in,
                              void* d_out, int out_size, void* d_ws, size_t ws_size,
                              hipStream_t stream) {
    const float* feat   = (const float*)d_in[0];
    const int*   src    = (const int*)d_in[1];
    const int*   dst    = (const int*)d_in[2];
    const float* W_src  = (const float*)d_in[3];
    const float* attn_l = (const float*)d_in[4];
    const float* attn_r = (const float*)d_in[5];
    const float* hop_l  = (const float*)d_in[6];
    const float* hop_r  = (const float*)d_in[7];
    const float* pos    = (const float*)d_in[8];
    const float* bias   = (const float*)d_in[9];
    float* out = (float*)d_out;

    // workspace carve
    char* p = (char*)d_ws;
    auto alloc = [&](size_t bytes) {
        char* r = p;
        p += (bytes + 255) & ~(size_t)255;
        return r;
    };
    float*  fs   = (float*)alloc((size_t)NN * 256 * 4);   // h0 fp32 (epilogue exactness)
    __half* fs16 = (__half*)alloc((size_t)NN * 256 * 2);  // h0 fp16 (gather copy)
    __half* h1   = (__half*)alloc((size_t)NN * 256 * 2);
    __half* h2   = (__half*)alloc((size_t)NN * 256 * 2);
    __half* h3   = (__half*)alloc((size_t)NN * 256 * 2);
    int*   offs = (int*)alloc((size_t)(NN + 1) * 4);
    int*   cnt  = (int*)alloc((size_t)NN * 4);
    int*   cur  = (int*)alloc((size_t)NN * 4);
    int*   bsum = (int*)alloc(256);
    float* el   = (float*)alloc((size_t)NN * 4 * 4);
    float* er   = (float*)alloc((size_t)NN * 4 * 4);
    int*   ssrc = (int*)alloc((size_t)EE * 4);
    float* alog = (float*)alloc((size_t)EE * 4 * 4);
    short* Wh   = (short*)alloc((size_t)256 * 256 * 2);
    short* Wl   = (short*)alloc((size_t)256 * 256 * 2);

    const int nScan = (NN + 1023) / 1024; // 49

    // 1) W -> fragment-ordered bf16 hi/lo, then feat_src = feat @ W^T via MFMA
    conv_w<<<256, 256, 0, stream>>>(W_src, Wh, Wl);
    gemm_mfma<<<(NN + 31) / 32, 256, 0, stream>>>(feat, Wh, Wl, attn_l, attn_r,
                                                  fs, fs16, el, er, NN);
    // 2) CSR build
    hipMemsetAsync(cnt, 0, (size_t)NN * 4, stream);
    count_k<<<(EE + 255) / 256, 256, 0, stream>>>(dst, cnt, EE);
    scan1<<<nScan, 256, 0, stream>>>(cnt, offs, bsum, NN);
    scan2<<<1, 64, 0, stream>>>(bsum, nScan);
    scan3<<<nScan, 256, 0, stream>>>(offs, bsum, cur, NN, EE);
    scatter_edges<<<(EE + 255) / 256, 256, 0, stream>>>(src, dst, (const float4*)el,
                                                        (const float4*)er, cur, ssrc,
                                                        (float4*)alog, EE);
    // 3) edge softmax
    edge_softmax<<<(NN * 4 + 255) / 256, 256, 0, stream>>>(offs, alog, NN);
    // 4) K=3 diffusion hops, fp16 state; one wave per node
    hop_kernel<<<(NN + 3) / 4, 256, 0, stream>>>(offs, ssrc, alog, fs16, h1);
    hop_kernel<<<(NN + 3) / 4, 256, 0, stream>>>(offs, ssrc, alog, h1, h2);
    hop_kernel<<<(NN + 3) / 4, 256, 0, stream>>>(offs, ssrc, alog, h2, h3);
    // 5) hop attention epilogue
    hop_attn<<<NN, 256, 0, stream>>>(fs, h1, h2, h3, pos, hop_l, hop_r, bias, out);
}

// Round 12
// 492.753 us; speedup vs baseline: 1.0998x; 1.0455x over previous
//
#include <hip/hip_runtime.h>
#include <hip/hip_bf16.h>
#include <hip/hip_fp16.h>

// Problem constants (match reference)
#define NN 50000
#define EE 800000
#define INF_ 256
#define HH 4
#define DD 64
#define KK 3
#define NEG_SLOPE 0.2f

struct __align__(8) half4 { __half2 a, b; };
struct __align__(8) short4s { short a, b, c, d; };

using bf16x8 = __attribute__((ext_vector_type(8))) short;
using f32x4  = __attribute__((ext_vector_type(4))) float;

__device__ __forceinline__ float lrelu(float x) {
    return x >= 0.0f ? x : NEG_SLOPE * x;
}

__device__ __forceinline__ float wave_sum(float v) {
    #pragma unroll
    for (int m = 1; m < 64; m <<= 1) v += __shfl_xor(v, m, 64);
    return v;
}

// fp32 <-> bf16 (RN-even) bit helpers
__device__ __forceinline__ short f2bf(float f) {
    union { float f; unsigned u; } v; v.f = f;
    unsigned r = (v.u + 0x7FFFu + ((v.u >> 16) & 1u)) >> 16;
    return (short)r;
}
__device__ __forceinline__ float bf2f(short s) {
    union { unsigned u; float f; } v; v.u = ((unsigned)(unsigned short)s) << 16;
    return v.f;
}

// ---------------- W -> bf16 hi/lo in MFMA-FRAGMENT ORDER (one-time, tiny).
// element i = (((w*8+kc)*4+tj)*64+lane)*8+e  maps to
// j = w*64 + tj*16 + (lane&15), k = kc*32 + (lane>>4)*8 + e.
__global__ __launch_bounds__(256) void conv_w(const float* __restrict__ W,
                                              short* __restrict__ Wh,
                                              short* __restrict__ Wl) {
    int i = blockIdx.x * 256 + threadIdx.x; // 65536 total
    int e    = i & 7;
    int lane = (i >> 3) & 63;
    int tj   = (i >> 9) & 3;
    int kc   = (i >> 11) & 7;
    int w    = i >> 14;
    int j = w * 64 + tj * 16 + (lane & 15);
    int k = kc * 32 + (lane >> 4) * 8 + e;
    float v = W[j * 256 + k];
    short h = f2bf(v);
    Wh[i] = h;
    Wl[i] = f2bf(v - bf2f(h));
}

// ---------------- pos/hop-attn constants: pC[h][k] = dot(pos[h,k,:], hl[h,:]),
// pR[h] = dot(pos[h,0,:], hr[h,:]). One wave.
__global__ void pconsts(const float* __restrict__ pos, const float* __restrict__ hl,
                        const float* __restrict__ hr, float* __restrict__ pC,
                        float* __restrict__ pR) {
    int d = threadIdx.x; // 0..63
    for (int h = 0; h < 4; ++h) {
        float vr = wave_sum(pos[(h * 4 + 0) * 64 + d] * hr[h * 64 + d]);
        if (d == 0) pR[h] = vr;
        for (int k = 0; k < 4; ++k) {
            float vl = wave_sum(pos[(h * 4 + k) * 64 + d] * hl[h * 64 + d]);
            if (d == 0) pC[h * 4 + k] = vl;
        }
    }
}

// ---------------- MFMA GEMM: C[m,j] = sum_k feat[m,k] * W[j,k], fp32 via bf16 hi/lo split.
// Block: 32 rows x 256 cols; 4 waves = 4 heads. Fused epilogue: el/er (edge logits)
// AND hdl0/hdr0 (hop-attention dots for hop 0) from in-register acc.
__global__ __launch_bounds__(256) void gemm_mfma(const float* __restrict__ A,
                                                 const short* __restrict__ Wh,
                                                 const short* __restrict__ Wl,
                                                 const float* __restrict__ al,
                                                 const float* __restrict__ ar,
                                                 const float* __restrict__ hl,
                                                 const float* __restrict__ hr,
                                                 float* __restrict__ C,
                                                 __half* __restrict__ C16,
                                                 float* __restrict__ el,
                                                 float* __restrict__ er,
                                                 float* __restrict__ hdl0,
                                                 float* __restrict__ hdr0, int M) {
    __shared__ short Ah[32 * 256];
    __shared__ short Al[32 * 256];
    int tid = threadIdx.x;
    int m0 = blockIdx.x * 32;

    // ---- stage A panel -> bf16 hi/lo in LDS, swizzled
    {
        int r4 = tid >> 6;
        int c4 = (tid & 63) * 4;
        #pragma unroll
        for (int it = 0; it < 8; ++it) {
            int row = it * 4 + r4;
            int m = m0 + row;
            float4 v = (m < M) ? *(const float4*)&A[(size_t)m * 256 + c4]
                               : make_float4(0.f, 0.f, 0.f, 0.f);
            short h0 = f2bf(v.x), h1 = f2bf(v.y), h2 = f2bf(v.z), h3 = f2bf(v.w);
            short l0 = f2bf(v.x - bf2f(h0)), l1 = f2bf(v.y - bf2f(h1));
            short l2 = f2bf(v.z - bf2f(h2)), l3 = f2bf(v.w - bf2f(h3));
            int cs = c4 ^ ((row & 7) << 3);
            short4s sh = { h0, h1, h2, h3 };
            short4s sl = { l0, l1, l2, l3 };
            *(short4s*)&Ah[row * 256 + cs] = sh;
            *(short4s*)&Al[row * 256 + cs] = sl;
        }
    }
    __syncthreads();

    int w = tid >> 6;
    int lane = tid & 63;
    int lrow = lane & 15;
    int lk = lane >> 4;
    int j0 = w * 64;

    f32x4 acc[2][4] = {};

    #pragma unroll
    for (int kc = 0; kc < 8; ++kc) {
        int kbase = kc * 32 + lk * 8;
        int fbase = (((w * 8 + kc) * 4) * 64 + lane) * 8;
        bf16x8 bh[4], bl[4], ah[2], alo[2];
        #pragma unroll
        for (int tj = 0; tj < 4; ++tj) {
            bh[tj] = *(const bf16x8*)&Wh[fbase + tj * 64 * 8];
            bl[tj] = *(const bf16x8*)&Wl[fbase + tj * 64 * 8];
        }
        #pragma unroll
        for (int tm = 0; tm < 2; ++tm) {
            int row = tm * 16 + lrow;
            int ks = kbase ^ ((row & 7) << 3);
            ah[tm]  = *(const bf16x8*)&Ah[row * 256 + ks];
            alo[tm] = *(const bf16x8*)&Al[row * 256 + ks];
        }
        #pragma unroll
        for (int tm = 0; tm < 2; ++tm)
            #pragma unroll
            for (int tj = 0; tj < 4; ++tj) {
                acc[tm][tj] = __builtin_amdgcn_mfma_f32_16x16x32_bf16(ah[tm],  bh[tj], acc[tm][tj], 0, 0, 0);
                acc[tm][tj] = __builtin_amdgcn_mfma_f32_16x16x32_bf16(alo[tm], bh[tj], acc[tm][tj], 0, 0, 0);
                acc[tm][tj] = __builtin_amdgcn_mfma_f32_16x16x32_bf16(ah[tm],  bl[tj], acc[tm][tj], 0, 0, 0);
            }
    }

    // ---- store C (fp32) + C16 (fp16). C/D layout: col = lane&15, row = (lane>>4)*4 + reg.
    #pragma unroll
    for (int tm = 0; tm < 2; ++tm)
        #pragma unroll
        for (int tj = 0; tj < 4; ++tj)
            #pragma unroll
            for (int r = 0; r < 4; ++r) {
                int m = m0 + tm * 16 + lk * 4 + r;
                if (m < M) {
                    int j = j0 + tj * 16 + lrow;
                    float x = acc[tm][tj][r];
                    C[(size_t)m * 256 + j] = x;
                    C16[(size_t)m * 256 + j] = __float2half(x);
                }
            }

    // ---- fused epilogue: el/er + hdl0/hdr0 for head w
    float alj[4], arj[4], hlj[4], hrj[4];
    #pragma unroll
    for (int tj = 0; tj < 4; ++tj) {
        int j = j0 + tj * 16 + lrow;
        alj[tj] = al[j]; arj[tj] = ar[j];
        hlj[tj] = hl[j]; hrj[tj] = hr[j];
    }
    #pragma unroll
    for (int tm = 0; tm < 2; ++tm)
        #pragma unroll
        for (int r = 0; r < 4; ++r) {
            float pl = acc[tm][0][r] * alj[0] + acc[tm][1][r] * alj[1] +
                       acc[tm][2][r] * alj[2] + acc[tm][3][r] * alj[3];
            float pr = acc[tm][0][r] * arj[0] + acc[tm][1][r] * arj[1] +
                       acc[tm][2][r] * arj[2] + acc[tm][3][r] * arj[3];
            float ph = acc[tm][0][r] * hlj[0] + acc[tm][1][r] * hlj[1] +
                       acc[tm][2][r] * hlj[2] + acc[tm][3][r] * hlj[3];
            float pq = acc[tm][0][r] * hrj[0] + acc[tm][1][r] * hrj[1] +
                       acc[tm][2][r] * hrj[2] + acc[tm][3][r] * hrj[3];
            #pragma unroll
            for (int msk = 1; msk < 16; msk <<= 1) {
                pl += __shfl_xor(pl, msk, 64);
                pr += __shfl_xor(pr, msk, 64);
                ph += __shfl_xor(ph, msk, 64);
                pq += __shfl_xor(pq, msk, 64);
            }
            if (lrow == 0) {
                int m = m0 + tm * 16 + lk * 4 + r;
                if (m < M) {
                    el[m * 4 + w] = pl;  er[m * 4 + w] = pr;
                    hdl0[m * 4 + w] = ph; hdr0[m * 4 + w] = pq;
                }
            }
        }
}

// ---------------- CSR build
__global__ void count_k(const int* __restrict__ dst, int* __restrict__ cnt, int E) {
    int e = blockIdx.x * 256 + threadIdx.x;
    if (e < E) atomicAdd(&cnt[dst[e]], 1);
}

__global__ __launch_bounds__(256) void scan1(const int* __restrict__ counts,
                                             int* __restrict__ offs,
                                             int* __restrict__ bsums, int n) {
    __shared__ int sh[256];
    int b = blockIdx.x, t = threadIdx.x;
    int base = b * 1024 + t * 4;
    int v[4];
    #pragma unroll
    for (int i = 0; i < 4; ++i) v[i] = (base + i < n) ? counts[base + i] : 0;
    int tsum = v[0] + v[1] + v[2] + v[3];
    sh[t] = tsum; __syncthreads();
    for (int off = 1; off < 256; off <<= 1) {
        int x = (t >= off) ? sh[t - off] : 0;
        __syncthreads();
        sh[t] += x;
        __syncthreads();
    }
    int run = sh[t] - tsum;
    #pragma unroll
    for (int i = 0; i < 4; ++i) { if (base + i < n) offs[base + i] = run; run += v[i]; }
    if (t == 255) bsums[b] = sh[255];
}

__global__ void scan2(int* bsums, int nb) {
    if (threadIdx.x == 0 && blockIdx.x == 0) {
        int run = 0;
        for (int i = 0; i < nb; ++i) { int v = bsums[i]; bsums[i] = run; run += v; }
    }
}

__global__ __launch_bounds__(256) void scan3(int* __restrict__ offs,
                                             const int* __restrict__ bsums,
                                             int* __restrict__ cursor, int n, int E) {
    int b = blockIdx.x;
    int base = b * 1024 + threadIdx.x * 4;
    int add = bsums[b];
    #pragma unroll
    for (int i = 0; i < 4; ++i) {
        if (base + i < n) {
            int v = offs[base + i] + add;
            offs[base + i] = v;
            cursor[base + i] = v;
        }
    }
    if (b == 0 && threadIdx.x == 0) offs[n] = E;
}

// ---------------- scatter edges into CSR slots + compute leaky logits
__global__ void scatter_edges(const int* __restrict__ src, const int* __restrict__ dst,
                              const float4* __restrict__ el4, const float4* __restrict__ er4,
                              int* __restrict__ cursor, int* __restrict__ ssrc,
                              float4* __restrict__ alog, int E) {
    int e = blockIdx.x * 256 + threadIdx.x;
    if (e >= E) return;
    int s = src[e], d = dst[e];
    int slot = atomicAdd(&cursor[d], 1);
    ssrc[slot] = s;
    float4 a = el4[s], b = er4[d];
    float4 o;
    o.x = lrelu(a.x + b.x);
    o.y = lrelu(a.y + b.y);
    o.z = lrelu(a.z + b.z);
    o.w = lrelu(a.w + b.w);
    alog[slot] = o;
}

// ---------------- per-(node,head) edge softmax (in place on alog)
__global__ __launch_bounds__(256) void edge_softmax(const int* __restrict__ offs,
                                                    float* __restrict__ alog, int n) {
    int t = blockIdx.x * 256 + threadIdx.x;
    if (t >= n * 4) return;
    int node = t >> 2, h = t & 3;
    int o0 = offs[node], o1 = offs[node + 1];
    if (o0 >= o1) return;
    float m = -1e30f;
    for (int i = o0; i < o1; ++i) m = fmaxf(m, alog[i * 4 + h]);
    float s = 0.f;
    for (int i = o0; i < o1; ++i) {
        float v = expf(alog[i * 4 + h] - m);
        alog[i * 4 + h] = v;
        s += v;
    }
    float inv = 1.0f / s;
    for (int i = o0; i < o1; ++i) alog[i * 4 + h] *= inv;
}

// ---------------- one diffusion hop (fp16 gather, fp32 accumulate, fp16 store)
// One WAVE per node. Fused epilogue: hdl[n,h] = dot(h_row, hop_l) from fp32 regs.
__global__ __launch_bounds__(256) void hop_kernel(const int* __restrict__ offs,
                                                  const int* __restrict__ ssrc,
                                                  const float* __restrict__ alog,
                                                  const __half* __restrict__ hin,
                                                  __half* __restrict__ hout,
                                                  const float* __restrict__ hl,
                                                  float* __restrict__ hdl) {
    int w = threadIdx.x >> 6;
    int n = blockIdx.x * 4 + w;
    if (n >= NN) return;
    int lane = threadIdx.x & 63;
    int h = lane >> 4;
    int col = lane * 4;
    int o0 = offs[n], o1 = offs[n + 1];
    float4 acc0 = make_float4(0.f, 0.f, 0.f, 0.f);
    float4 acc1 = make_float4(0.f, 0.f, 0.f, 0.f);
    float4 acc2 = make_float4(0.f, 0.f, 0.f, 0.f);
    float4 acc3 = make_float4(0.f, 0.f, 0.f, 0.f);
    int i = o0;
    for (; i + 4 <= o1; i += 4) {
        int s0 = ssrc[i], s1 = ssrc[i + 1], s2 = ssrc[i + 2], s3 = ssrc[i + 3];
        float a0 = alog[i * 4 + h];
        float a1 = alog[(i + 1) * 4 + h];
        float a2 = alog[(i + 2) * 4 + h];
        float a3 = alog[(i + 3) * 4 + h];
        half4 v0 = *(const half4*)&hin[(size_t)s0 * 256 + col];
        half4 v1 = *(const half4*)&hin[(size_t)s1 * 256 + col];
        half4 v2 = *(const half4*)&hin[(size_t)s2 * 256 + col];
        half4 v3 = *(const half4*)&hin[(size_t)s3 * 256 + col];
        float2 f0a = __half22float2(v0.a), f0b = __half22float2(v0.b);
        float2 f1a = __half22float2(v1.a), f1b = __half22float2(v1.b);
        float2 f2a = __half22float2(v2.a), f2b = __half22float2(v2.b);
        float2 f3a = __half22float2(v3.a), f3b = __half22float2(v3.b);
        acc0.x = fmaf(a0, f0a.x, acc0.x); acc0.y = fmaf(a0, f0a.y, acc0.y);
        acc0.z = fmaf(a0, f0b.x, acc0.z); acc0.w = fmaf(a0, f0b.y, acc0.w);
        acc1.x = fmaf(a1, f1a.x, acc1.x); acc1.y = fmaf(a1, f1a.y, acc1.y);
        acc1.z = fmaf(a1, f1b.x, acc1.z); acc1.w = fmaf(a1, f1b.y, acc1.w);
        acc2.x = fmaf(a2, f2a.x, acc2.x); acc2.y = fmaf(a2, f2a.y, acc2.y);
        acc2.z = fmaf(a2, f2b.x, acc2.z); acc2.w = fmaf(a2, f2b.y, acc2.w);
        acc3.x = fmaf(a3, f3a.x, acc3.x); acc3.y = fmaf(a3, f3a.y, acc3.y);
        acc3.z = fmaf(a3, f3b.x, acc3.z); acc3.w = fmaf(a3, f3b.y, acc3.w);
    }
    for (; i < o1; ++i) {
        int s0 = ssrc[i];
        float a0 = alog[i * 4 + h];
        half4 v0 = *(const half4*)&hin[(size_t)s0 * 256 + col];
        float2 f0a = __half22float2(v0.a), f0b = __half22float2(v0.b);
        acc0.x = fmaf(a0, f0a.x, acc0.x); acc0.y = fmaf(a0, f0a.y, acc0.y);
        acc0.z = fmaf(a0, f0b.x, acc0.z); acc0.w = fmaf(a0, f0b.y, acc0.w);
    }
    float4 r;
    r.x = (acc0.x + acc1.x) + (acc2.x + acc3.x);
    r.y = (acc0.y + acc1.y) + (acc2.y + acc3.y);
    r.z = (acc0.z + acc1.z) + (acc2.z + acc3.z);
    r.w = (acc0.w + acc1.w) + (acc2.w + acc3.w);
    half4 q;
    q.a = __floats2half2_rn(r.x, r.y);
    q.b = __floats2half2_rn(r.z, r.w);
    *(half4*)&hout[(size_t)n * 256 + col] = q;
    // ---- fused hop-attention dot for this hop: sum over d within 16-lane head group
    float pd = r.x * hl[col] + r.y * hl[col + 1] + r.z * hl[col + 2] + r.w * hl[col + 3];
    #pragma unroll
    for (int msk = 1; msk < 16; msk <<= 1) pd += __shfl_xor(pd, msk, 64);
    if ((lane & 15) == 0) hdl[n * 4 + h] = pd;
}

// ---------------- hop-attention weights: per (n,h) 4-way softmax -> float4
__global__ __launch_bounds__(256) void hop_wts(const float* __restrict__ hdl0,
                                               const float* __restrict__ hdl1,
                                               const float* __restrict__ hdl2,
                                               const float* __restrict__ hdl3,
                                               const float* __restrict__ hdr0,
                                               const float* __restrict__ pC,
                                               const float* __restrict__ pR,
                                               float4* __restrict__ wts, int n4) {
    int t = blockIdx.x * 256 + threadIdx.x;
    if (t >= n4) return;
    int h = t & 3;
    float ar = hdr0[t] + pR[h];
    float l0 = lrelu(hdl0[t] + pC[h * 4 + 0] + ar);
    float l1 = lrelu(hdl1[t] + pC[h * 4 + 1] + ar);
    float l2 = lrelu(hdl2[t] + pC[h * 4 + 2] + ar);
    float l3 = lrelu(hdl3[t] + pC[h * 4 + 3] + ar);
    float mm = fmaxf(fmaxf(l0, l1), fmaxf(l2, l3));
    float e0 = expf(l0 - mm), e1 = expf(l1 - mm), e2 = expf(l2 - mm), e3 = expf(l3 - mm);
    float inv = 1.0f / (e0 + e1 + e2 + e3);
    wts[t] = make_float4(e0 * inv, e1 * inv, e2 * inv, e3 * inv);
}

// ---------------- hop attention combine: pure streaming, no reductions
__global__ __launch_bounds__(256) void hop_attn(const float* __restrict__ h0,
                                                const __half* __restrict__ h1,
                                                const __half* __restrict__ h2,
                                                const __half* __restrict__ h3,
                                                const float* __restrict__ pos,
                                                const float4* __restrict__ wts,
                                                const float* __restrict__ bias,
                                                float* __restrict__ out) {
    int n = blockIdx.x, tid = threadIdx.x;
    int h = tid >> 6, d = tid & 63;
    size_t idx = (size_t)n * 256 + tid;
    float4 w = wts[n * 4 + h];
    float v0 = h0[idx] + pos[(h * 4 + 0) * 64 + d];
    float v1 = __half2float(h1[idx]) + pos[(h * 4 + 1) * 64 + d];
    float v2 = __half2float(h2[idx]) + pos[(h * 4 + 2) * 64 + d];
    float v3 = __half2float(h3[idx]) + pos[(h * 4 + 3) * 64 + d];
    out[idx] = v0 * w.x + v1 * w.y + v2 * w.z + v3 * w.w + bias[tid];
}

extern "C" void kernel_launch(void* const* d_in, const int* in_sizes, int n_in,
                              void* d_out, int out_size, void* d_ws, size_t ws_size,
                              hipStream_t stream) {
    const float* feat   = (const float*)d_in[0];
    const int*   src    = (const int*)d_in[1];
    const int*   dst    = (const int*)d_in[2];
    const float* W_src  = (const float*)d_in[3];
    const float* attn_l = (const float*)d_in[4];
    const float* attn_r = (const float*)d_in[5];
    const float* hop_l  = (const float*)d_in[6];
    const float* hop_r  = (const float*)d_in[7];
    const float* pos    = (const float*)d_in[8];
    const float* bias   = (const float*)d_in[9];
    float* out = (float*)d_out;

    // workspace carve
    char* p = (char*)d_ws;
    auto alloc = [&](size_t bytes) {
        char* r = p;
        p += (bytes + 255) & ~(size_t)255;
        return r;
    };
    float*  fs   = (float*)alloc((size_t)NN * 256 * 4);   // h0 fp32
    __half* fs16 = (__half*)alloc((size_t)NN * 256 * 2);  // h0 fp16 (gather copy)
    __half* h1   = (__half*)alloc((size_t)NN * 256 * 2);
    __half* h2   = (__half*)alloc((size_t)NN * 256 * 2);
    __half* h3   = (__half*)alloc((size_t)NN * 256 * 2);
    int*   offs = (int*)alloc((size_t)(NN + 1) * 4);
    int*   cnt  = (int*)alloc((size_t)NN * 4);
    int*   cur  = (int*)alloc((size_t)NN * 4);
    int*   bsum = (int*)alloc(256);
    float* el   = (float*)alloc((size_t)NN * 4 * 4);
    float* er   = (float*)alloc((size_t)NN * 4 * 4);
    int*   ssrc = (int*)alloc((size_t)EE * 4);
    float* alog = (float*)alloc((size_t)EE * 4 * 4);
    short* Wh   = (short*)alloc((size_t)256 * 256 * 2);
    short* Wl   = (short*)alloc((size_t)256 * 256 * 2);
    float* hdl0 = (float*)alloc((size_t)NN * 4 * 4);
    float* hdr0 = (float*)alloc((size_t)NN * 4 * 4);
    float* hdl1 = (float*)alloc((size_t)NN * 4 * 4);
    float* hdl2 = (float*)alloc((size_t)NN * 4 * 4);
    float* hdl3 = (float*)alloc((size_t)NN * 4 * 4);
    float* wts  = (float*)alloc((size_t)NN * 4 * 16);
    float* pC   = (float*)alloc(16 * 4);
    float* pR   = (float*)alloc(4 * 4);

    const int nScan = (NN + 1023) / 1024; // 49

    // 1) W -> fragment-ordered bf16 hi/lo; pos/hop constants; MFMA GEMM w/ fused dots
    conv_w<<<256, 256, 0, stream>>>(W_src, Wh, Wl);
    pconsts<<<1, 64, 0, stream>>>(pos, hop_l, hop_r, pC, pR);
    gemm_mfma<<<(NN + 31) / 32, 256, 0, stream>>>(feat, Wh, Wl, attn_l, attn_r,
                                                  hop_l, hop_r, fs, fs16, el, er,
                                                  hdl0, hdr0, NN);
    // 2) CSR build
    hipMemsetAsync(cnt, 0, (size_t)NN * 4, stream);
    count_k<<<(EE + 255) / 256, 256, 0, stream>>>(dst, cnt, EE);
    scan1<<<nScan, 256, 0, stream>>>(cnt, offs, bsum, NN);
    scan2<<<1, 64, 0, stream>>>(bsum, nScan);
    scan3<<<nScan, 256, 0, stream>>>(offs, bsum, cur, NN, EE);
    scatter_edges<<<(EE + 255) / 256, 256, 0, stream>>>(src, dst, (const float4*)el,
                                                        (const float4*)er, cur, ssrc,
                                                        (float4*)alog, EE);
    // 3) edge softmax
    edge_softmax<<<(NN * 4 + 255) / 256, 256, 0, stream>>>(offs, alog, NN);
    // 4) K=3 diffusion hops, fp16 state, fused hop-attention dots
    hop_kernel<<<(NN + 3) / 4, 256, 0, stream>>>(offs, ssrc, alog, fs16, h1, hop_l, hdl1);
    hop_kernel<<<(NN + 3) / 4, 256, 0, stream>>>(offs, ssrc, alog, h1, h2, hop_l, hdl2);
    hop_kernel<<<(NN + 3) / 4, 256, 0, stream>>>(offs, ssrc, alog, h2, h3, hop_l, hdl3);
    // 5) hop-attention weights (per (n,h) softmax), then streaming combine
    hop_wts<<<(NN * 4 + 255) / 256, 256, 0, stream>>>(hdl0, hdl1, hdl2, hdl3, hdr0,
                                                      pC, pR, (float4*)wts, NN * 4);
    hop_attn<<<NN, 256, 0, stream>>>(fs, h1, h2, h3, pos, (const float4*)wts, bias, out);
}

// Round 13
// 478.183 us; speedup vs baseline: 1.1333x; 1.0305x over previous
//
#include <hip/hip_runtime.h>
#include <hip/hip_bf16.h>
#include <hip/hip_fp16.h>

// Problem constants (match reference)
#define NN 50000
#define EE 800000
#define INF_ 256
#define HH 4
#define DD 64
#define KK 3
#define NEG_SLOPE 0.2f

struct __align__(8) half4 { __half2 a, b; };
struct __align__(8) short4s { short a, b, c, d; };

using bf16x8 = __attribute__((ext_vector_type(8))) short;
using f32x4  = __attribute__((ext_vector_type(4))) float;

__device__ __forceinline__ float lrelu(float x) {
    return x >= 0.0f ? x : NEG_SLOPE * x;
}

__device__ __forceinline__ float wave_sum(float v) {
    #pragma unroll
    for (int m = 1; m < 64; m <<= 1) v += __shfl_xor(v, m, 64);
    return v;
}

// fp32 <-> bf16 (RN-even) bit helpers
__device__ __forceinline__ short f2bf(float f) {
    union { float f; unsigned u; } v; v.f = f;
    unsigned r = (v.u + 0x7FFFu + ((v.u >> 16) & 1u)) >> 16;
    return (short)r;
}
__device__ __forceinline__ float bf2f(short s) {
    union { unsigned u; float f; } v; v.u = ((unsigned)(unsigned short)s) << 16;
    return v.f;
}

// ---------------- W -> bf16 hi/lo in MFMA-FRAGMENT ORDER (one-time, tiny).
__global__ __launch_bounds__(256) void conv_w(const float* __restrict__ W,
                                              short* __restrict__ Wh,
                                              short* __restrict__ Wl) {
    int i = blockIdx.x * 256 + threadIdx.x; // 65536 total
    int e    = i & 7;
    int lane = (i >> 3) & 63;
    int tj   = (i >> 9) & 3;
    int kc   = (i >> 11) & 7;
    int w    = i >> 14;
    int j = w * 64 + tj * 16 + (lane & 15);
    int k = kc * 32 + (lane >> 4) * 8 + e;
    float v = W[j * 256 + k];
    short h = f2bf(v);
    Wh[i] = h;
    Wl[i] = f2bf(v - bf2f(h));
}

// ---------------- pos/hop-attn constants: pC[h][k] = dot(pos[h,k,:], hl[h,:]),
// pR[h] = dot(pos[h,0,:], hr[h,:]). One wave.
__global__ void pconsts(const float* __restrict__ pos, const float* __restrict__ hl,
                        const float* __restrict__ hr, float* __restrict__ pC,
                        float* __restrict__ pR) {
    int d = threadIdx.x; // 0..63
    for (int h = 0; h < 4; ++h) {
        float vr = wave_sum(pos[(h * 4 + 0) * 64 + d] * hr[h * 64 + d]);
        if (d == 0) pR[h] = vr;
        for (int k = 0; k < 4; ++k) {
            float vl = wave_sum(pos[(h * 4 + k) * 64 + d] * hl[h * 64 + d]);
            if (d == 0) pC[h * 4 + k] = vl;
        }
    }
}

// ---------------- MFMA GEMM: C[m,j] = sum_k feat[m,k] * W[j,k], fp32 via bf16 hi/lo split.
__global__ __launch_bounds__(256) void gemm_mfma(const float* __restrict__ A,
                                                 const short* __restrict__ Wh,
                                                 const short* __restrict__ Wl,
                                                 const float* __restrict__ al,
                                                 const float* __restrict__ ar,
                                                 const float* __restrict__ hl,
                                                 const float* __restrict__ hr,
                                                 float* __restrict__ C,
                                                 __half* __restrict__ C16,
                                                 float* __restrict__ el,
                                                 float* __restrict__ er,
                                                 float* __restrict__ hdl0,
                                                 float* __restrict__ hdr0, int M) {
    __shared__ short Ah[32 * 256];
    __shared__ short Al[32 * 256];
    int tid = threadIdx.x;
    int m0 = blockIdx.x * 32;

    // ---- stage A panel -> bf16 hi/lo in LDS, swizzled
    {
        int r4 = tid >> 6;
        int c4 = (tid & 63) * 4;
        #pragma unroll
        for (int it = 0; it < 8; ++it) {
            int row = it * 4 + r4;
            int m = m0 + row;
            float4 v = (m < M) ? *(const float4*)&A[(size_t)m * 256 + c4]
                               : make_float4(0.f, 0.f, 0.f, 0.f);
            short h0 = f2bf(v.x), h1 = f2bf(v.y), h2 = f2bf(v.z), h3 = f2bf(v.w);
            short l0 = f2bf(v.x - bf2f(h0)), l1 = f2bf(v.y - bf2f(h1));
            short l2 = f2bf(v.z - bf2f(h2)), l3 = f2bf(v.w - bf2f(h3));
            int cs = c4 ^ ((row & 7) << 3);
            short4s sh = { h0, h1, h2, h3 };
            short4s sl = { l0, l1, l2, l3 };
            *(short4s*)&Ah[row * 256 + cs] = sh;
            *(short4s*)&Al[row * 256 + cs] = sl;
        }
    }
    __syncthreads();

    int w = tid >> 6;
    int lane = tid & 63;
    int lrow = lane & 15;
    int lk = lane >> 4;
    int j0 = w * 64;

    f32x4 acc[2][4] = {};

    #pragma unroll
    for (int kc = 0; kc < 8; ++kc) {
        int kbase = kc * 32 + lk * 8;
        int fbase = (((w * 8 + kc) * 4) * 64 + lane) * 8;
        bf16x8 bh[4], bl[4], ah[2], alo[2];
        #pragma unroll
        for (int tj = 0; tj < 4; ++tj) {
            bh[tj] = *(const bf16x8*)&Wh[fbase + tj * 64 * 8];
            bl[tj] = *(const bf16x8*)&Wl[fbase + tj * 64 * 8];
        }
        #pragma unroll
        for (int tm = 0; tm < 2; ++tm) {
            int row = tm * 16 + lrow;
            int ks = kbase ^ ((row & 7) << 3);
            ah[tm]  = *(const bf16x8*)&Ah[row * 256 + ks];
            alo[tm] = *(const bf16x8*)&Al[row * 256 + ks];
        }
        #pragma unroll
        for (int tm = 0; tm < 2; ++tm)
            #pragma unroll
            for (int tj = 0; tj < 4; ++tj) {
                acc[tm][tj] = __builtin_amdgcn_mfma_f32_16x16x32_bf16(ah[tm],  bh[tj], acc[tm][tj], 0, 0, 0);
                acc[tm][tj] = __builtin_amdgcn_mfma_f32_16x16x32_bf16(alo[tm], bh[tj], acc[tm][tj], 0, 0, 0);
                acc[tm][tj] = __builtin_amdgcn_mfma_f32_16x16x32_bf16(ah[tm],  bl[tj], acc[tm][tj], 0, 0, 0);
            }
    }

    // ---- store C (fp32) + C16 (fp16). C/D layout: col = lane&15, row = (lane>>4)*4 + reg.
    #pragma unroll
    for (int tm = 0; tm < 2; ++tm)
        #pragma unroll
        for (int tj = 0; tj < 4; ++tj)
            #pragma unroll
            for (int r = 0; r < 4; ++r) {
                int m = m0 + tm * 16 + lk * 4 + r;
                if (m < M) {
                    int j = j0 + tj * 16 + lrow;
                    float x = acc[tm][tj][r];
                    C[(size_t)m * 256 + j] = x;
                    C16[(size_t)m * 256 + j] = __float2half(x);
                }
            }

    // ---- fused epilogue: el/er + hdl0/hdr0 for head w
    float alj[4], arj[4], hlj[4], hrj[4];
    #pragma unroll
    for (int tj = 0; tj < 4; ++tj) {
        int j = j0 + tj * 16 + lrow;
        alj[tj] = al[j]; arj[tj] = ar[j];
        hlj[tj] = hl[j]; hrj[tj] = hr[j];
    }
    #pragma unroll
    for (int tm = 0; tm < 2; ++tm)
        #pragma unroll
        for (int r = 0; r < 4; ++r) {
            float pl = acc[tm][0][r] * alj[0] + acc[tm][1][r] * alj[1] +
                       acc[tm][2][r] * alj[2] + acc[tm][3][r] * alj[3];
            float pr = acc[tm][0][r] * arj[0] + acc[tm][1][r] * arj[1] +
                       acc[tm][2][r] * arj[2] + acc[tm][3][r] * arj[3];
            float ph = acc[tm][0][r] * hlj[0] + acc[tm][1][r] * hlj[1] +
                       acc[tm][2][r] * hlj[2] + acc[tm][3][r] * hlj[3];
            float pq = acc[tm][0][r] * hrj[0] + acc[tm][1][r] * hrj[1] +
                       acc[tm][2][r] * hrj[2] + acc[tm][3][r] * hrj[3];
            #pragma unroll
            for (int msk = 1; msk < 16; msk <<= 1) {
                pl += __shfl_xor(pl, msk, 64);
                pr += __shfl_xor(pr, msk, 64);
                ph += __shfl_xor(ph, msk, 64);
                pq += __shfl_xor(pq, msk, 64);
            }
            if (lrow == 0) {
                int m = m0 + tm * 16 + lk * 4 + r;
                if (m < M) {
                    el[m * 4 + w] = pl;  er[m * 4 + w] = pr;
                    hdl0[m * 4 + w] = ph; hdr0[m * 4 + w] = pq;
                }
            }
        }
}

// ---------------- CSR build
__global__ void count_k(const int* __restrict__ dst, int* __restrict__ cnt, int E) {
    int e = blockIdx.x * 256 + threadIdx.x;
    if (e < E) atomicAdd(&cnt[dst[e]], 1);
}

__global__ __launch_bounds__(256) void scan1(const int* __restrict__ counts,
                                             int* __restrict__ offs,
                                             int* __restrict__ bsums, int n) {
    __shared__ int sh[256];
    int b = blockIdx.x, t = threadIdx.x;
    int base = b * 1024 + t * 4;
    int v[4];
    #pragma unroll
    for (int i = 0; i < 4; ++i) v[i] = (base + i < n) ? counts[base + i] : 0;
    int tsum = v[0] + v[1] + v[2] + v[3];
    sh[t] = tsum; __syncthreads();
    for (int off = 1; off < 256; off <<= 1) {
        int x = (t >= off) ? sh[t - off] : 0;
        __syncthreads();
        sh[t] += x;
        __syncthreads();
    }
    int run = sh[t] - tsum;
    #pragma unroll
    for (int i = 0; i < 4; ++i) { if (base + i < n) offs[base + i] = run; run += v[i]; }
    if (t == 255) bsums[b] = sh[255];
}

__global__ void scan2(int* bsums, int nb) {
    if (threadIdx.x == 0 && blockIdx.x == 0) {
        int run = 0;
        for (int i = 0; i < nb; ++i) { int v = bsums[i]; bsums[i] = run; run += v; }
    }
}

__global__ __launch_bounds__(256) void scan3(int* __restrict__ offs,
                                             const int* __restrict__ bsums,
                                             int* __restrict__ cursor, int n, int E) {
    int b = blockIdx.x;
    int base = b * 1024 + threadIdx.x * 4;
    int add = bsums[b];
    #pragma unroll
    for (int i = 0; i < 4; ++i) {
        if (base + i < n) {
            int v = offs[base + i] + add;
            offs[base + i] = v;
            cursor[base + i] = v;
        }
    }
    if (b == 0 && threadIdx.x == 0) offs[n] = E;
}

// ---------------- scatter edges into CSR slots + compute leaky logits
__global__ void scatter_edges(const int* __restrict__ src, const int* __restrict__ dst,
                              const float4* __restrict__ el4, const float4* __restrict__ er4,
                              int* __restrict__ cursor, int* __restrict__ ssrc,
                              float4* __restrict__ alog, int E) {
    int e = blockIdx.x * 256 + threadIdx.x;
    if (e >= E) return;
    int s = src[e], d = dst[e];
    int slot = atomicAdd(&cursor[d], 1);
    ssrc[slot] = s;
    float4 a = el4[s], b = er4[d];
    float4 o;
    o.x = lrelu(a.x + b.x);
    o.y = lrelu(a.y + b.y);
    o.z = lrelu(a.z + b.z);
    o.w = lrelu(a.w + b.w);
    alog[slot] = o;
}

// ---------------- per-(node,head) edge softmax (in place on alog)
__global__ __launch_bounds__(256) void edge_softmax(const int* __restrict__ offs,
                                                    float* __restrict__ alog, int n) {
    int t = blockIdx.x * 256 + threadIdx.x;
    if (t >= n * 4) return;
    int node = t >> 2, h = t & 3;
    int o0 = offs[node], o1 = offs[node + 1];
    if (o0 >= o1) return;
    float m = -1e30f;
    for (int i = o0; i < o1; ++i) m = fmaxf(m, alog[i * 4 + h]);
    float s = 0.f;
    for (int i = o0; i < o1; ++i) {
        float v = expf(alog[i * 4 + h] - m);
        alog[i * 4 + h] = v;
        s += v;
    }
    float inv = 1.0f / s;
    for (int i = o0; i < o1; ++i) alog[i * 4 + h] *= inv;
}

// ---------------- gather loop shared by hop kernels: returns the wave's float4 slice
__device__ __forceinline__ float4 hop_gather(const int* __restrict__ offs,
                                             const int* __restrict__ ssrc,
                                             const float* __restrict__ alog,
                                             const __half* __restrict__ hin,
                                             int n, int lane, int h, int col) {
    int o0 = offs[n], o1 = offs[n + 1];
    float4 acc0 = make_float4(0.f, 0.f, 0.f, 0.f);
    float4 acc1 = make_float4(0.f, 0.f, 0.f, 0.f);
    float4 acc2 = make_float4(0.f, 0.f, 0.f, 0.f);
    float4 acc3 = make_float4(0.f, 0.f, 0.f, 0.f);
    int i = o0;
    for (; i + 4 <= o1; i += 4) {
        int s0 = ssrc[i], s1 = ssrc[i + 1], s2 = ssrc[i + 2], s3 = ssrc[i + 3];
        float a0 = alog[i * 4 + h];
        float a1 = alog[(i + 1) * 4 + h];
        float a2 = alog[(i + 2) * 4 + h];
        float a3 = alog[(i + 3) * 4 + h];
        half4 v0 = *(const half4*)&hin[(size_t)s0 * 256 + col];
        half4 v1 = *(const half4*)&hin[(size_t)s1 * 256 + col];
        half4 v2 = *(const half4*)&hin[(size_t)s2 * 256 + col];
        half4 v3 = *(const half4*)&hin[(size_t)s3 * 256 + col];
        float2 f0a = __half22float2(v0.a), f0b = __half22float2(v0.b);
        float2 f1a = __half22float2(v1.a), f1b = __half22float2(v1.b);
        float2 f2a = __half22float2(v2.a), f2b = __half22float2(v2.b);
        float2 f3a = __half22float2(v3.a), f3b = __half22float2(v3.b);
        acc0.x = fmaf(a0, f0a.x, acc0.x); acc0.y = fmaf(a0, f0a.y, acc0.y);
        acc0.z = fmaf(a0, f0b.x, acc0.z); acc0.w = fmaf(a0, f0b.y, acc0.w);
        acc1.x = fmaf(a1, f1a.x, acc1.x); acc1.y = fmaf(a1, f1a.y, acc1.y);
        acc1.z = fmaf(a1, f1b.x, acc1.z); acc1.w = fmaf(a1, f1b.y, acc1.w);
        acc2.x = fmaf(a2, f2a.x, acc2.x); acc2.y = fmaf(a2, f2a.y, acc2.y);
        acc2.z = fmaf(a2, f2b.x, acc2.z); acc2.w = fmaf(a2, f2b.y, acc2.w);
        acc3.x = fmaf(a3, f3a.x, acc3.x); acc3.y = fmaf(a3, f3a.y, acc3.y);
        acc3.z = fmaf(a3, f3b.x, acc3.z); acc3.w = fmaf(a3, f3b.y, acc3.w);
    }
    for (; i < o1; ++i) {
        int s0 = ssrc[i];
        float a0 = alog[i * 4 + h];
        half4 v0 = *(const half4*)&hin[(size_t)s0 * 256 + col];
        float2 f0a = __half22float2(v0.a), f0b = __half22float2(v0.b);
        acc0.x = fmaf(a0, f0a.x, acc0.x); acc0.y = fmaf(a0, f0a.y, acc0.y);
        acc0.z = fmaf(a0, f0b.x, acc0.z); acc0.w = fmaf(a0, f0b.y, acc0.w);
    }
    float4 r;
    r.x = (acc0.x + acc1.x) + (acc2.x + acc3.x);
    r.y = (acc0.y + acc1.y) + (acc2.y + acc3.y);
    r.z = (acc0.z + acc1.z) + (acc2.z + acc3.z);
    r.w = (acc0.w + acc1.w) + (acc2.w + acc3.w);
    return r;
}

// ---------------- hops 1,2: gather + store fp16 + fused hop-attn dot
__global__ __launch_bounds__(256) void hop_kernel(const int* __restrict__ offs,
                                                  const int* __restrict__ ssrc,
                                                  const float* __restrict__ alog,
                                                  const __half* __restrict__ hin,
                                                  __half* __restrict__ hout,
                                                  const float* __restrict__ hl,
                                                  float* __restrict__ hdl) {
    int w = threadIdx.x >> 6;
    int n = blockIdx.x * 4 + w;
    if (n >= NN) return;
    int lane = threadIdx.x & 63;
    int h = lane >> 4;
    int col = lane * 4;
    float4 r = hop_gather(offs, ssrc, alog, hin, n, lane, h, col);
    half4 q;
    q.a = __floats2half2_rn(r.x, r.y);
    q.b = __floats2half2_rn(r.z, r.w);
    *(half4*)&hout[(size_t)n * 256 + col] = q;
    float pd = r.x * hl[col] + r.y * hl[col + 1] + r.z * hl[col + 2] + r.w * hl[col + 3];
    #pragma unroll
    for (int msk = 1; msk < 16; msk <<= 1) pd += __shfl_xor(pd, msk, 64);
    if ((lane & 15) == 0) hdl[n * 4 + h] = pd;
}

// ---------------- hop 3 FUSED with hop-attention: no h3 materialization.
// Gather h3 row into registers, compute hdl3 in-wave, softmax weights, stream
// h0/h1/h2 rows + pos + bias, write final output.
__global__ __launch_bounds__(256) void hop3_fused(const int* __restrict__ offs,
                                                  const int* __restrict__ ssrc,
                                                  const float* __restrict__ alog,
                                                  const __half* __restrict__ h2in,
                                                  const float* __restrict__ h0,
                                                  const __half* __restrict__ h1,
                                                  const float* __restrict__ hdl0,
                                                  const float* __restrict__ hdl1,
                                                  const float* __restrict__ hdl2,
                                                  const float* __restrict__ hdr0,
                                                  const float* __restrict__ pC,
                                                  const float* __restrict__ pR,
                                                  const float* __restrict__ pos,
                                                  const float* __restrict__ bias,
                                                  const float* __restrict__ hl,
                                                  float* __restrict__ out) {
    int w = threadIdx.x >> 6;
    int n = blockIdx.x * 4 + w;
    if (n >= NN) return;
    int lane = threadIdx.x & 63;
    int h = lane >> 4;
    int col = lane * 4;
    float4 r = hop_gather(offs, ssrc, alog, h2in, n, lane, h, col);
    // hdl3 for this (n,h): reduce over the 16-lane head group (all lanes get it)
    float pd = r.x * hl[col] + r.y * hl[col + 1] + r.z * hl[col + 2] + r.w * hl[col + 3];
    #pragma unroll
    for (int msk = 1; msk < 16; msk <<= 1) pd += __shfl_xor(pd, msk, 64);
    // hop-attention weights
    int nh = n * 4 + h;
    float ar = hdr0[nh] + pR[h];
    float l0 = lrelu(hdl0[nh] + pC[h * 4 + 0] + ar);
    float l1 = lrelu(hdl1[nh] + pC[h * 4 + 1] + ar);
    float l2 = lrelu(hdl2[nh] + pC[h * 4 + 2] + ar);
    float l3 = lrelu(pd       + pC[h * 4 + 3] + ar);
    float mm = fmaxf(fmaxf(l0, l1), fmaxf(l2, l3));
    float e0 = expf(l0 - mm), e1 = expf(l1 - mm), e2 = expf(l2 - mm), e3 = expf(l3 - mm);
    float inv = 1.0f / (e0 + e1 + e2 + e3);
    float w0 = e0 * inv, w1 = e1 * inv, w2 = e2 * inv, w3 = e3 * inv;
    // combine
    int dh = col & 63;
    float4 p0 = *(const float4*)&pos[(h * 4 + 0) * 64 + dh];
    float4 p1 = *(const float4*)&pos[(h * 4 + 1) * 64 + dh];
    float4 p2 = *(const float4*)&pos[(h * 4 + 2) * 64 + dh];
    float4 p3 = *(const float4*)&pos[(h * 4 + 3) * 64 + dh];
    float4 b4 = *(const float4*)&bias[col];
    float4 v0 = *(const float4*)&h0[(size_t)n * 256 + col];
    half4 q1 = *(const half4*)&h1[(size_t)n * 256 + col];
    half4 q2 = *(const half4*)&h2in[(size_t)n * 256 + col];
    float2 f1a = __half22float2(q1.a), f1b = __half22float2(q1.b);
    float2 f2a = __half22float2(q2.a), f2b = __half22float2(q2.b);
    float4 o;
    o.x = (v0.x + p0.x) * w0 + (f1a.x + p1.x) * w1 + (f2a.x + p2.x) * w2 + (r.x + p3.x) * w3 + b4.x;
    o.y = (v0.y + p0.y) * w0 + (f1a.y + p1.y) * w1 + (f2a.y + p2.y) * w2 + (r.y + p3.y) * w3 + b4.y;
    o.z = (v0.z + p0.z) * w0 + (f1b.x + p1.z) * w1 + (f2b.x + p2.z) * w2 + (r.z + p3.z) * w3 + b4.z;
    o.w = (v0.w + p0.w) * w0 + (f1b.y + p1.w) * w1 + (f2b.y + p2.w) * w2 + (r.w + p3.w) * w3 + b4.w;
    *(float4*)&out[(size_t)n * 256 + col] = o;
}

extern "C" void kernel_launch(void* const* d_in, const int* in_sizes, int n_in,
                              void* d_out, int out_size, void* d_ws, size_t ws_size,
                              hipStream_t stream) {
    const float* feat   = (const float*)d_in[0];
    const int*   src    = (const int*)d_in[1];
    const int*   dst    = (const int*)d_in[2];
    const float* W_src  = (const float*)d_in[3];
    const float* attn_l = (const float*)d_in[4];
    const float* attn_r = (const float*)d_in[5];
    const float* hop_l  = (const float*)d_in[6];
    const float* hop_r  = (const float*)d_in[7];
    const float* pos    = (const float*)d_in[8];
    const float* bias   = (const float*)d_in[9];
    float* out = (float*)d_out;

    // workspace carve
    char* p = (char*)d_ws;
    auto alloc = [&](size_t bytes) {
        char* r = p;
        p += (bytes + 255) & ~(size_t)255;
        return r;
    };
    float*  fs   = (float*)alloc((size_t)NN * 256 * 4);   // h0 fp32
    __half* fs16 = (__half*)alloc((size_t)NN * 256 * 2);  // h0 fp16 (gather copy)
    __half* h1   = (__half*)alloc((size_t)NN * 256 * 2);
    __half* h2   = (__half*)alloc((size_t)NN * 256 * 2);
    int*   offs = (int*)alloc((size_t)(NN + 1) * 4);
    int*   cnt  = (int*)alloc((size_t)NN * 4);
    int*   cur  = (int*)alloc((size_t)NN * 4);
    int*   bsum = (int*)alloc(256);
    float* el   = (float*)alloc((size_t)NN * 4 * 4);
    float* er   = (float*)alloc((size_t)NN * 4 * 4);
    int*   ssrc = (int*)alloc((size_t)EE * 4);
    float* alog = (float*)alloc((size_t)EE * 4 * 4);
    short* Wh   = (short*)alloc((size_t)256 * 256 * 2);
    short* Wl   = (short*)alloc((size_t)256 * 256 * 2);
    float* hdl0 = (float*)alloc((size_t)NN * 4 * 4);
    float* hdr0 = (float*)alloc((size_t)NN * 4 * 4);
    float* hdl1 = (float*)alloc((size_t)NN * 4 * 4);
    float* hdl2 = (float*)alloc((size_t)NN * 4 * 4);
    float* pC   = (float*)alloc(16 * 4);
    float* pR   = (float*)alloc(4 * 4);

    const int nScan = (NN + 1023) / 1024; // 49

    // 1) W -> fragment-ordered bf16 hi/lo; pos/hop constants; MFMA GEMM w/ fused dots
    conv_w<<<256, 256, 0, stream>>>(W_src, Wh, Wl);
    pconsts<<<1, 64, 0, stream>>>(pos, hop_l, hop_r, pC, pR);
    gemm_mfma<<<(NN + 31) / 32, 256, 0, stream>>>(feat, Wh, Wl, attn_l, attn_r,
                                                  hop_l, hop_r, fs, fs16, el, er,
                                                  hdl0, hdr0, NN);
    // 2) CSR build
    hipMemsetAsync(cnt, 0, (size_t)NN * 4, stream);
    count_k<<<(EE + 255) / 256, 256, 0, stream>>>(dst, cnt, EE);
    scan1<<<nScan, 256, 0, stream>>>(cnt, offs, bsum, NN);
    scan2<<<1, 64, 0, stream>>>(bsum, nScan);
    scan3<<<nScan, 256, 0, stream>>>(offs, bsum, cur, NN, EE);
    scatter_edges<<<(EE + 255) / 256, 256, 0, stream>>>(src, dst, (const float4*)el,
                                                        (const float4*)er, cur, ssrc,
                                                        (float4*)alog, EE);
    // 3) edge softmax
    edge_softmax<<<(NN * 4 + 255) / 256, 256, 0, stream>>>(offs, alog, NN);
    // 4) hops 1,2 (fp16 state + fused dots); hop 3 fused with hop-attention
    hop_kernel<<<(NN + 3) / 4, 256, 0, stream>>>(offs, ssrc, alog, fs16, h1, hop_l, hdl1);
    hop_kernel<<<(NN + 3) / 4, 256, 0, stream>>>(offs, ssrc, alog, h1, h2, hop_l, hdl2);
    hop3_fused<<<(NN + 3) / 4, 256, 0, stream>>>(offs, ssrc, alog, h2, fs, h1,
                                                 hdl0, hdl1, hdl2, hdr0, pC, pR,
                                                 pos, bias, hop_l, out);
}